// Round 1
// baseline (2002.611 us; speedup 1.0000x reference)
//
#include <hip/hip_runtime.h>
#include <math.h>

#define B_   16
#define CIN  64
#define COUT 128
#define H_   128
#define W_   128

#define TS   16   // spatial tile (16x16 outputs per block)
#define COB  8    // couts per block
#define TIN  18   // TS + 2 halo
#define LDP  20   // padded LDS row stride

// ---- prep: w_spline[co][ci][kh][kw] = sum_g spline_weights[co][ci][kh][kw][g]
__global__ __launch_bounds__(256) void spline_sum_kernel(const float* __restrict__ sw,
                                                         float* __restrict__ wsum) {
    int i = blockIdx.x * 256 + threadIdx.x;
    if (i < COUT * CIN * 9) {
        const float4 v = *reinterpret_cast<const float4*>(sw + (size_t)i * 4);
        wsum[i] = v.x + v.y + v.z + v.w;
    }
}

// ---- main: out = conv(x, wsum) + conv(silu(x), wb), SAME pad, stride 1
__global__ __launch_bounds__(256) void kan_conv(const float* __restrict__ x,
                                                const float* __restrict__ wsp,
                                                const float* __restrict__ wb,
                                                float* __restrict__ out) {
    __shared__ float xs[TIN][LDP];
    __shared__ float ss[TIN][LDP];

    const int t  = threadIdx.x;
    const int tx = t & 15;
    const int ty = t >> 4;
    const int tile = blockIdx.x;           // 64 tiles: 8 across W, 8 across H
    const int w0 = (tile & 7) * TS;
    const int h0 = (tile >> 3) * TS;
    const int co0 = blockIdx.y * COB;
    const int b   = blockIdx.z;

    float acc[COB];
#pragma unroll
    for (int i = 0; i < COB; ++i) acc[i] = 0.f;

    const float* xb = x + (size_t)b * CIN * H_ * W_;

    for (int ci = 0; ci < CIN; ++ci) {
        __syncthreads();   // protect previous iteration's LDS reads
        const float* xc = xb + (size_t)ci * H_ * W_;
        // stage 18x18 halo tile: raw x and silu(x)
        for (int p = t; p < TIN * TIN; p += 256) {
            int r = p / TIN, c = p - r * TIN;
            int ih = h0 + r - 1, iw = w0 + c - 1;
            float v = 0.f;
            if (ih >= 0 && ih < H_ && iw >= 0 && iw < W_) v = xc[ih * W_ + iw];
            xs[r][c] = v;
            ss[r][c] = v / (1.f + expf(-v));   // silu; silu(0)=0 matches zero-pad
        }
        __syncthreads();

        float xv[9], sv[9];
#pragma unroll
        for (int kh = 0; kh < 3; ++kh)
#pragma unroll
            for (int kw = 0; kw < 3; ++kw) {
                xv[kh * 3 + kw] = xs[ty + kh][tx + kw];
                sv[kh * 3 + kw] = ss[ty + kh][tx + kw];
            }

#pragma unroll
        for (int co = 0; co < COB; ++co) {
            // block-uniform addresses -> scalar (s_load) weight fetches
            const float* w1 = wsp + ((size_t)(co0 + co) * CIN + ci) * 9;
            const float* w2 = wb  + ((size_t)(co0 + co) * CIN + ci) * 9;
#pragma unroll
            for (int k = 0; k < 9; ++k)
                acc[co] += xv[k] * w1[k] + sv[k] * w2[k];
        }
    }

    const int oh = h0 + ty, ow = w0 + tx;
#pragma unroll
    for (int co = 0; co < COB; ++co)
        out[(((size_t)b * COUT + (co0 + co)) * H_ + oh) * W_ + ow] = acc[co];
}

extern "C" void kernel_launch(void* const* d_in, const int* in_sizes, int n_in,
                              void* d_out, int out_size, void* d_ws, size_t ws_size,
                              hipStream_t stream) {
    const float* x  = (const float*)d_in[0];
    const float* sw = (const float*)d_in[1];  // (COUT,CIN,3,3,G)
    const float* wb = (const float*)d_in[2];  // (COUT,CIN,3,3)
    float* out  = (float*)d_out;
    float* wsum = (float*)d_ws;               // COUT*CIN*9 floats = 288 KiB

    spline_sum_kernel<<<(COUT * CIN * 9 + 255) / 256, 256, 0, stream>>>(sw, wsum);

    dim3 grid(64, COUT / COB, B_);
    kan_conv<<<grid, 256, 0, stream>>>(x, wsum, wb, out);
}

// Round 4
// 200.018 us; speedup vs baseline: 10.0121x; 10.0121x over previous
//
#include <hip/hip_runtime.h>
#include <math.h>

#define B_    16
#define CIN   64
#define COUT  128
#define H_    128
#define W_    128
#define CI2   128            // 2*CIN (x ++ silu(x))
#define KTOT  1152           // 9 taps * CI2

typedef __bf16 bf16x8 __attribute__((ext_vector_type(8)));
typedef float  f32x4  __attribute__((ext_vector_type(4)));

#define XT_BYTES  ((size_t)B_ * H_ * W_ * CI2 * 2)   // 67,108,864
#define WC_BYTES  ((size_t)COUT * KTOT * 2)          // 294,912
#define Z_OFF     (XT_BYTES + WC_BYTES)
#define WS_NEED   (Z_OFF + 4096)

// ---------- prep 1: weights -> Wc[co][k] bf16, k = tap*128 + ci2 ----------
// ci2 < 64: sum_g spline_weights[co][ci2][tap][g]; ci2 >= 64: basis[co][ci2-64][tap]
__global__ __launch_bounds__(256) void w_prep(const float* __restrict__ sw,
                                              const float* __restrict__ bw,
                                              __bf16* __restrict__ wc,
                                              float* __restrict__ zp) {
    const int i = blockIdx.x * 256 + threadIdx.x;
    if (blockIdx.x == 0) zp[threadIdx.x] = 0.f;  // zeros page (1 KiB)
    if (i >= COUT * KTOT) return;
    const int co = i / KTOT, k = i - co * KTOT;
    const int tap = k >> 7, ci2 = k & 127;
    float v;
    if (ci2 < CIN) {
        const float* p = sw + ((size_t)(co * CIN + ci2) * 9 + tap) * 4;
        v = p[0] + p[1] + p[2] + p[3];
    } else {
        v = bw[(size_t)(co * CIN + (ci2 - CIN)) * 9 + tap];
    }
    wc[(size_t)co * KTOT + k] = (__bf16)v;
}

// ---------- prep 2: x (NCHW fp32) -> Xt (NHWC bf16, ci2 = x ++ silu(x)) ----------
__global__ __launch_bounds__(256) void xt_prep(const float* __restrict__ x,
                                               __bf16* __restrict__ xt) {
    __shared__ __align__(16) __bf16 tile[64][136];   // [w][ci2], padded row
    const int t  = threadIdx.x;
    const int w0 = blockIdx.x * 64;    // 0 or 64
    const int h  = blockIdx.y;
    const int b  = blockIdx.z;
    const float* xb = x + ((size_t)(b * CIN) * H_ + h) * W_ + w0;
#pragma unroll
    for (int rep = 0; rep < 16; ++rep) {
        const int idx = rep * 256 + t;
        const int ci = idx >> 6, w = idx & 63;
        const float v = xb[(size_t)ci * H_ * W_ + w];
        tile[w][ci]       = (__bf16)v;
        tile[w][CIN + ci] = (__bf16)(v / (1.f + __expf(-v)));  // silu
    }
    __syncthreads();
    __bf16* ob = xt + (((size_t)b * H_ + h) * W_ + w0) * CI2;
#pragma unroll
    for (int rep = 0; rep < 4; ++rep) {
        const int idx = rep * 256 + t;          // 0..1023
        const int w = idx >> 4, sl = idx & 15;  // 16B chunk per thread
        *(bf16x8*)(ob + (size_t)w * CI2 + sl * 8) = *(const bf16x8*)(&tile[w][sl * 8]);
    }
}

// ---------- main: implicit-GEMM MFMA conv ----------
// block: 128 couts x (8h x 16w) positions; 4 waves as 2(m) x 2(n)
// LDS: halo tile 10x18 pos x 128 ci2 bf16, 16B-chunk XOR-swizzled by (pos&15)
__global__ __launch_bounds__(256, 2) void kan_mfma(const __bf16* __restrict__ xt,
                                                   const __bf16* __restrict__ wc,
                                                   const float* __restrict__ zp,
                                                   float* __restrict__ out) {
    __shared__ __align__(16) char xs[2880 * 16];   // 180 pos * 256B = 46080B
    const int t    = threadIdx.x;
    const int lane = t & 63, wave = t >> 6;
    const int wm = wave >> 1, wn = wave & 1;
    const int l15 = lane & 15, lq = lane >> 4;
    const int w0 = blockIdx.x * 16, h0 = blockIdx.y * 8, b = blockIdx.z;

    // ---- stage halo tile once: global_load_lds 16B, pre-swizzled source
    const size_t xbase = (size_t)b * (H_ * W_ * CI2);
#pragma unroll
    for (int i = 0; i < 12; ++i) {
        const int s = i * 256 + t;               // linear 16B slot
        if (s < 2880) {
            const int pos = s >> 4, q = s & 15;
            const int ih = pos / 18, iw = pos - ih * 18;
            const int gh = h0 + ih - 1, gw = w0 + iw - 1;
            const int chunk = q ^ (pos & 15);    // involution: LDS slot q holds chunk q^..
            const void* src;
            if (gh >= 0 && gh < H_ && gw >= 0 && gw < W_)
                src = (const void*)(xt + xbase + ((size_t)(gh * W_ + gw)) * CI2 + chunk * 8);
            else
                src = (const void*)zp;           // zero page
            __builtin_amdgcn_global_load_lds(
                (const __attribute__((address_space(1))) unsigned int*)src,
                (__attribute__((address_space(3))) unsigned int*)(xs + s * 16), 16, 0, 0);
        }
    }
    __syncthreads();   // the only barrier

    f32x4 acc[4][4] = {};

    const __bf16* arow[4];
#pragma unroll
    for (int m = 0; m < 4; ++m)
        arow[m] = wc + (size_t)(wm * 64 + m * 16 + l15) * KTOT + lq * 8;

    int pos0[4];
#pragma unroll
    for (int n = 0; n < 4; ++n) pos0[n] = (wn * 4 + n) * 18 + l15;

    for (int kh = 0; kh < 3; ++kh) {
        for (int kw = 0; kw < 3; ++kw) {
            const int tap  = kh * 3 + kw;
            const int dpos = kh * 18 + kw;
#pragma unroll
            for (int ks = 0; ks < 4; ++ks) {
                bf16x8 af[4], bfr[4];
#pragma unroll
                for (int m = 0; m < 4; ++m)
                    af[m] = *(const bf16x8*)(arow[m] + tap * 128 + ks * 32);
#pragma unroll
                for (int n = 0; n < 4; ++n) {
                    const int pos = pos0[n] + dpos;
                    const int swz = (ks * 4 + lq) ^ (pos & 15);
                    bfr[n] = *(const bf16x8*)(xs + pos * 256 + swz * 16);
                }
#pragma unroll
                for (int m = 0; m < 4; ++m)
#pragma unroll
                    for (int n = 0; n < 4; ++n)
                        acc[m][n] = __builtin_amdgcn_mfma_f32_16x16x32_bf16(
                            af[m], bfr[n], acc[m][n], 0, 0, 0);
            }
        }
    }

    // ---- epilogue: D row = co (lq*4+r), col = position (l15)
    float* ob = out + (size_t)b * COUT * H_ * W_;
#pragma unroll
    for (int m = 0; m < 4; ++m) {
        const int co = wm * 64 + m * 16 + lq * 4;
#pragma unroll
        for (int n = 0; n < 4; ++n) {
            const int ph = wn * 4 + n;
            float* p = ob + ((size_t)co * H_ + (h0 + ph)) * W_ + (w0 + l15);
#pragma unroll
            for (int r = 0; r < 4; ++r)
                p[(size_t)r * H_ * W_] = acc[m][n][r];
        }
    }
}

// ---------- fallback (round-0 fp32 path, used only if ws too small) ----------
#define TS   16
#define COB  8
#define TIN  18
__global__ __launch_bounds__(256) void spline_sum_kernel(const float* __restrict__ sw,
                                                         float* __restrict__ wsum) {
    int i = blockIdx.x * 256 + threadIdx.x;
    if (i < COUT * CIN * 9) {
        const float4 v = *reinterpret_cast<const float4*>(sw + (size_t)i * 4);
        wsum[i] = v.x + v.y + v.z + v.w;
    }
}
__global__ __launch_bounds__(256) void kan_conv(const float* __restrict__ x,
                                                const float* __restrict__ wsp,
                                                const float* __restrict__ wb,
                                                float* __restrict__ out) {
    __shared__ float xsm[TIN][20];
    __shared__ float ssm[TIN][20];
    const int t = threadIdx.x, tx = t & 15, ty = t >> 4;
    const int w0 = (blockIdx.x & 7) * TS, h0 = (blockIdx.x >> 3) * TS;
    const int co0 = blockIdx.y * COB, b = blockIdx.z;
    float acc[COB];
#pragma unroll
    for (int i = 0; i < COB; ++i) acc[i] = 0.f;
    const float* xb = x + (size_t)b * CIN * H_ * W_;
    for (int ci = 0; ci < CIN; ++ci) {
        __syncthreads();
        const float* xc = xb + (size_t)ci * H_ * W_;
        for (int p = t; p < TIN * TIN; p += 256) {
            int r = p / TIN, c = p - r * TIN;
            int ih = h0 + r - 1, iw = w0 + c - 1;
            float v = 0.f;
            if (ih >= 0 && ih < H_ && iw >= 0 && iw < W_) v = xc[ih * W_ + iw];
            xsm[r][c] = v;
            ssm[r][c] = v / (1.f + expf(-v));
        }
        __syncthreads();
        float xv[9], sv[9];
#pragma unroll
        for (int kh = 0; kh < 3; ++kh)
#pragma unroll
            for (int kw = 0; kw < 3; ++kw) {
                xv[kh * 3 + kw] = xsm[ty + kh][tx + kw];
                sv[kh * 3 + kw] = ssm[ty + kh][tx + kw];
            }
#pragma unroll
        for (int co = 0; co < COB; ++co) {
            const float* w1 = wsp + ((size_t)(co0 + co) * CIN + ci) * 9;
            const float* w2 = wb  + ((size_t)(co0 + co) * CIN + ci) * 9;
#pragma unroll
            for (int k = 0; k < 9; ++k)
                acc[co] += xv[k] * w1[k] + sv[k] * w2[k];
        }
    }
    const int oh = h0 + ty, ow = w0 + tx;
#pragma unroll
    for (int co = 0; co < COB; ++co)
        out[(((size_t)b * COUT + (co0 + co)) * H_ + oh) * W_ + ow] = acc[co];
}

extern "C" void kernel_launch(void* const* d_in, const int* in_sizes, int n_in,
                              void* d_out, int out_size, void* d_ws, size_t ws_size,
                              hipStream_t stream) {
    const float* x  = (const float*)d_in[0];
    const float* sw = (const float*)d_in[1];   // (COUT,CIN,3,3,4)
    const float* bw = (const float*)d_in[2];   // (COUT,CIN,3,3)
    float* out = (float*)d_out;

    if (ws_size >= WS_NEED) {
        __bf16* xt = (__bf16*)d_ws;
        __bf16* wc = (__bf16*)((char*)d_ws + XT_BYTES);
        float*  zp = (float*)((char*)d_ws + Z_OFF);
        w_prep<<<(COUT * KTOT + 255) / 256, 256, 0, stream>>>(sw, bw, wc, zp);
        xt_prep<<<dim3(2, H_, B_), 256, 0, stream>>>(x, xt);
        kan_mfma<<<dim3(W_ / 16, H_ / 8, B_), 256, 0, stream>>>(xt, wc, zp, out);
    } else {
        float* wsum = (float*)d_ws;   // 288 KiB
        spline_sum_kernel<<<(COUT * CIN * 9 + 255) / 256, 256, 0, stream>>>(sw, wsum);
        kan_conv<<<dim3(64, COUT / COB, B_), 256, 0, stream>>>(x, wsum, bw, out);
    }
}